// Round 12
// baseline (268.401 us; speedup 1.0000x reference)
//
#include <hip/hip_runtime.h>
#include <stdint.h>

// Problem constants (fixed by the reference)
#define T_TOKENS 16384   // B*S = 4*4096
#define HDIM     2048
#define NEXP     8
#define NCHUNK   (HDIM / 256)                    // 8 chunks of 256 floats
#define TPW      2                               // tokens per wave-iteration
#define WPB      8                               // waves per block (512 threads)
#define NITER    2                               // pair-iterations per wave
#define TOK_PER_BLOCK (WPB * TPW * NITER)        // 32
#define NBLOCKS  (T_TOKENS / TOK_PER_BLOCK)      // 512 -> exactly 2 blocks/CU

typedef const __attribute__((address_space(1))) uint32_t* gas_ptr;
typedef __attribute__((address_space(3))) uint32_t*       las_ptr;

__device__ __forceinline__ float dot4(float4 a, float4 b) {
    return a.x * b.x + a.y * b.y + a.z * b.z + a.w * b.w;
}

// Value-splitting butterfly stage: 2*D live accumulators -> D.
template <int D>
__device__ __forceinline__ void reduce_stage(float (&acc)[TPW * NEXP], int lane) {
    const bool upper = (lane & D) != 0;
#pragma unroll
    for (int i = 0; i < D; ++i) {
        float send = upper ? acc[i] : acc[i + D];
        float recv = __shfl_xor(send, D, 64);
        float keep = upper ? acc[i + D] : acc[i];
        acc[i] = keep + recv;
    }
}

// Round-6 post-mortem: atomic finale removed -> router dropped 143 -> ~55us.
// Remaining gap to the ~25-30us floor: one-shot blocks with a lockstep
// vmcnt(0)+barrier serialize memory against compute (all 16 waves/CU park
// together, then all compute together), plus block churn. This kernel
// (fifth resubmission after infra failures -- still unmeasured): 512 blocks x
// 32 tokens, gate staged ONCE per block, ONE barrier, then 2 independent
// per-wave pair-iterations with NO further barriers -- next pair's 16 x-loads
// issue under the previous pair's reduce/top-2/store phase, and 16 mutually-
// slipping waves/CU cover the rest of the latency.
__global__ __launch_bounds__(512, 4) void router_fused(
    const float* __restrict__ x, const float* __restrict__ gate_w,
    float* __restrict__ out, int* __restrict__ gpart) {
    __shared__ float lds_gate[NEXP * HDIM];  // 65536 bytes
    __shared__ int   hist[NEXP];

    const int tid  = threadIdx.x;
    const int lane = tid & 63;
    const int wave = tid >> 6;
    if (tid < NEXP) hist[tid] = 0;

    // Stage gate_w (8x2048 f32 = 64 KB) via async global->LDS DMA: per wave,
    // 8 issues x 1 KB. Zero VGPR round-trip for gate data (round-5 verified).
    const float4* g4 = (const float4*)gate_w;
    float4* l4 = (float4*)lds_gate;
#pragma unroll
    for (int i = 0; i < (NEXP * HDIM / 4) / 512; ++i) {
        __builtin_amdgcn_global_load_lds(
            (gas_ptr)(g4 + i * 512 + wave * 64 + lane),
            (las_ptr)(l4 + i * 512 + wave * 64), 16, 0, 0);
    }

    const int block_tok = blockIdx.x * TOK_PER_BLOCK;
    const float4* x4 = (const float4*)x;
    const int row = HDIM / 4;  // 512 float4 per token

    // Preload iteration 0's token pair (16 global_load_dwordx4 in flight).
    float4 xv[TPW][NCHUNK];
#pragma unroll
    for (int t = 0; t < TPW; ++t)
#pragma unroll
        for (int c = 0; c < NCHUNK; ++c)
            xv[t][c] = x4[(size_t)(block_tok + wave * TPW + t) * row + c * 64 + lane];

    __syncthreads();  // ONE barrier: gate DMA drained (vmcnt covers x too); hist init

#pragma unroll
    for (int it = 0; it < NITER; ++it) {
        const int t_base = block_tok + it * (WPB * TPW) + wave * TPW;

        float acc[TPW * NEXP];
#pragma unroll
        for (int v = 0; v < TPW * NEXP; ++v) acc[v] = 0.f;

        // Pure LDS + FMA block; all indices compile-time.
#pragma unroll
        for (int c = 0; c < NCHUNK; ++c) {
#pragma unroll
            for (int e = 0; e < NEXP; ++e) {
                float4 gv = l4[e * row + c * 64 + lane];
#pragma unroll
                for (int t = 0; t < TPW; ++t)
                    acc[t * NEXP + e] += dot4(xv[t][c], gv);
            }
        }

        // xv is dead now: issue next iteration's loads HERE so they fly under
        // the reduce/top-2/store phase below (no barrier in the way).
        if (it + 1 < NITER) {
            const int nt = block_tok + (it + 1) * (WPB * TPW) + wave * TPW;
#pragma unroll
            for (int t = 0; t < TPW; ++t)
#pragma unroll
                for (int c = 0; c < NCHUNK; ++c)
                    xv[t][c] = x4[(size_t)(nt + t) * row + c * 64 + lane];
        }

        // Cross-lane reduce: 16 values over 64 lanes (bits 0-3), then fold 16/32.
        reduce_stage<8>(acc, lane);
        reduce_stage<4>(acc, lane);
        reduce_stage<2>(acc, lane);
        reduce_stage<1>(acc, lane);
        float v = acc[0];
        v += __shfl_xor(v, 16, 64);
        v += __shfl_xor(v, 32, 64);
        // Lane l holds the full logit for token t_base + ((l>>3)&1), expert l&7.
        const float logit = v;

        // Gather this token-group's 8 logits.
        const int base = lane & 56;
        float lg[NEXP];
#pragma unroll
        for (int e = 0; e < NEXP; ++e) lg[e] = __shfl(logit, base + e, 64);

        // top-2, lowest index wins ties (matches jax.lax.top_k)
        int i1 = 0; float m1 = lg[0];
#pragma unroll
        for (int e = 1; e < NEXP; ++e) {
            if (lg[e] > m1) { m1 = lg[e]; i1 = e; }
        }
        int i2 = 1; float m2 = -3.4e38f;
#pragma unroll
        for (int e = 0; e < NEXP; ++e) {
            if (e != i1 && lg[e] > m2) { m2 = lg[e]; i2 = e; }
        }

        // Renormalized softmax over the top-2 (other experts cancel exactly).
        const float r  = __expf(m2 - m1);  // <= 1
        const float w1 = 1.f / (1.f + r);
        const float w2 = 1.f - w1;

        const bool leader = ((lane & 7) == 0) && (lane < 16);  // lanes 0 and 8
        const int  tok    = t_base + (lane >> 3);
        if (leader) {
            out[tok * 2 + 0] = w1;
            out[tok * 2 + 1] = w2;
            out[2 * T_TOKENS + tok * 2 + 0] = (float)i1;  // indices as f32
            out[2 * T_TOKENS + tok * 2 + 1] = (float)i2;
            // Per-token expert counts into the block-level LDS histogram.
            atomicAdd(&hist[i1], 1);
            atomicAdd(&hist[i2], 1);
        }
    }
    __syncthreads();

    // Plain stores to this block's private slot. No global atomics, no fence.
    if (tid < NEXP) gpart[blockIdx.x * NEXP + tid] = hist[tid];
}

// Reduce the 512x8 partial-histogram table and compute the aux loss.
// Kernel boundary provides the global visibility ordering.
__global__ void router_aux(const int* __restrict__ gpart, float* __restrict__ out) {
    __shared__ int part[256];
    const int t = threadIdx.x;
    int s = 0;
#pragma unroll
    for (int i = 0; i < (NBLOCKS * NEXP) / 256; ++i)  // 16 iters, coalesced
        s += gpart[i * 256 + t];
    part[t] = s;  // thread t's sum is purely expert t&7 (256 % 8 == 0)
    __syncthreads();
    if (t < NEXP) {
        int c = 0;
#pragma unroll
        for (int i = 0; i < 256 / NEXP; ++i) c += part[t + i * NEXP];
        part[t] = c;  // per-expert total
    }
    __syncthreads();
    if (t == 0) {
        float m[NEXP];
        float ssum = 0.f;
#pragma unroll
        for (int e = 0; e < NEXP; ++e) {
            m[e] = (float)part[e] / (float)T_TOKENS;
            ssum += m[e];
        }
        const float mean = ssum / (float)NEXP;
        float var = 0.f;
#pragma unroll
        for (int e = 0; e < NEXP; ++e) {
            float d = m[e] - mean;
            var += d * d;
        }
        var /= (float)(NEXP - 1);            // unbiased (ddof=1), matches torch.var
        out[4 * T_TOKENS] = var * (float)NEXP;
    }
}

extern "C" void kernel_launch(void* const* d_in, const int* in_sizes, int n_in,
                              void* d_out, int out_size, void* d_ws, size_t ws_size,
                              hipStream_t stream) {
    const float* x  = (const float*)d_in[0];
    const float* gw = (const float*)d_in[1];
    float* out = (float*)d_out;
    int* gpart = (int*)d_ws;  // NBLOCKS*NEXP ints = 16 KB; every slot written,
                              // so no memset dispatch needed.

    router_fused<<<NBLOCKS, 512, 0, stream>>>(x, gw, out, gpart);
    router_aux<<<1, 256, 0, stream>>>(gpart, out);
}

// Round 13
// 229.301 us; speedup vs baseline: 1.1705x; 1.1705x over previous
//
#include <hip/hip_runtime.h>
#include <stdint.h>

// Problem constants (fixed by the reference)
#define T_TOKENS 16384   // B*S = 4*4096
#define HDIM     2048
#define NEXP     8
#define NCHUNK   (HDIM / 256)                    // 8 chunks of 256 floats
#define TPW      2                               // tokens per wave-iteration
#define WPB      8                               // waves per block (512 threads)
#define NITER    2                               // pair-iterations per wave
#define TOK_PER_BLOCK (WPB * TPW * NITER)        // 32
#define NBLOCKS  (T_TOKENS / TOK_PER_BLOCK)      // 512 -> exactly 2 blocks/CU

typedef const __attribute__((address_space(1))) uint32_t* gas_ptr;
typedef __attribute__((address_space(3))) uint32_t*       las_ptr;

__device__ __forceinline__ float dot4(float4 a, float4 b) {
    return a.x * b.x + a.y * b.y + a.z * b.z + a.w * b.w;
}

// Value-splitting butterfly stage: 2*D live accumulators -> D.
template <int D>
__device__ __forceinline__ void reduce_stage(float (&acc)[TPW * NEXP], int lane) {
    const bool upper = (lane & D) != 0;
#pragma unroll
    for (int i = 0; i < D; ++i) {
        float send = upper ? acc[i] : acc[i + D];
        float recv = __shfl_xor(send, D, 64);
        float keep = upper ? acc[i + D] : acc[i];
        acc[i] = keep + recv;
    }
}

// Round-12 post-mortem: the barrier-free NITER=2 schedule spilled (VGPR
// pinned at 64, WRITE_SIZE 196 MB of scratch write-back) because xv[2][8]
// (64 VGPRs) stays live across the reduce/top-2/store tail, and the
// allocator empirically lands at HALF the theoretical launch_bounds cap
// ((1024,8)->32, (256,6)->40, (512,4)->60-64) and spills rather than
// relaxing. SINGLE CHANGE this round: __launch_bounds__(512,4) -> (512,2).
// Theoretical cap 256; empirical ~128 >= peak live ~105 -> no spill.
// Achieved occupancy is LDS-capped at 2 blocks/CU (4 waves/SIMD) either
// way, and <=128 VGPRs keeps 4 waves/SIMD feasible -- the declared min
// costs nothing at runtime. Everything else byte-identical to Round 7 to
// preserve the A/B on the barrier-free-schedule hypothesis.
__global__ __launch_bounds__(512, 2) void router_fused(
    const float* __restrict__ x, const float* __restrict__ gate_w,
    float* __restrict__ out, int* __restrict__ gpart) {
    __shared__ float lds_gate[NEXP * HDIM];  // 65536 bytes
    __shared__ int   hist[NEXP];

    const int tid  = threadIdx.x;
    const int lane = tid & 63;
    const int wave = tid >> 6;
    if (tid < NEXP) hist[tid] = 0;

    // Stage gate_w (8x2048 f32 = 64 KB) via async global->LDS DMA: per wave,
    // 8 issues x 1 KB. Zero VGPR round-trip for gate data (round-5 verified).
    const float4* g4 = (const float4*)gate_w;
    float4* l4 = (float4*)lds_gate;
#pragma unroll
    for (int i = 0; i < (NEXP * HDIM / 4) / 512; ++i) {
        __builtin_amdgcn_global_load_lds(
            (gas_ptr)(g4 + i * 512 + wave * 64 + lane),
            (las_ptr)(l4 + i * 512 + wave * 64), 16, 0, 0);
    }

    const int block_tok = blockIdx.x * TOK_PER_BLOCK;
    const float4* x4 = (const float4*)x;
    const int row = HDIM / 4;  // 512 float4 per token

    // Preload iteration 0's token pair (16 global_load_dwordx4 in flight).
    float4 xv[TPW][NCHUNK];
#pragma unroll
    for (int t = 0; t < TPW; ++t)
#pragma unroll
        for (int c = 0; c < NCHUNK; ++c)
            xv[t][c] = x4[(size_t)(block_tok + wave * TPW + t) * row + c * 64 + lane];

    __syncthreads();  // ONE barrier: gate DMA drained (vmcnt covers x too); hist init

#pragma unroll
    for (int it = 0; it < NITER; ++it) {
        const int t_base = block_tok + it * (WPB * TPW) + wave * TPW;

        float acc[TPW * NEXP];
#pragma unroll
        for (int v = 0; v < TPW * NEXP; ++v) acc[v] = 0.f;

        // Pure LDS + FMA block; all indices compile-time.
#pragma unroll
        for (int c = 0; c < NCHUNK; ++c) {
#pragma unroll
            for (int e = 0; e < NEXP; ++e) {
                float4 gv = l4[e * row + c * 64 + lane];
#pragma unroll
                for (int t = 0; t < TPW; ++t)
                    acc[t * NEXP + e] += dot4(xv[t][c], gv);
            }
        }

        // xv is dead now: issue next iteration's loads HERE so they fly under
        // the reduce/top-2/store phase below (no barrier in the way).
        if (it + 1 < NITER) {
            const int nt = block_tok + (it + 1) * (WPB * TPW) + wave * TPW;
#pragma unroll
            for (int t = 0; t < TPW; ++t)
#pragma unroll
                for (int c = 0; c < NCHUNK; ++c)
                    xv[t][c] = x4[(size_t)(nt + t) * row + c * 64 + lane];
        }

        // Cross-lane reduce: 16 values over 64 lanes (bits 0-3), then fold 16/32.
        reduce_stage<8>(acc, lane);
        reduce_stage<4>(acc, lane);
        reduce_stage<2>(acc, lane);
        reduce_stage<1>(acc, lane);
        float v = acc[0];
        v += __shfl_xor(v, 16, 64);
        v += __shfl_xor(v, 32, 64);
        // Lane l holds the full logit for token t_base + ((l>>3)&1), expert l&7.
        const float logit = v;

        // Gather this token-group's 8 logits.
        const int base = lane & 56;
        float lg[NEXP];
#pragma unroll
        for (int e = 0; e < NEXP; ++e) lg[e] = __shfl(logit, base + e, 64);

        // top-2, lowest index wins ties (matches jax.lax.top_k)
        int i1 = 0; float m1 = lg[0];
#pragma unroll
        for (int e = 1; e < NEXP; ++e) {
            if (lg[e] > m1) { m1 = lg[e]; i1 = e; }
        }
        int i2 = 1; float m2 = -3.4e38f;
#pragma unroll
        for (int e = 0; e < NEXP; ++e) {
            if (e != i1 && lg[e] > m2) { m2 = lg[e]; i2 = e; }
        }

        // Renormalized softmax over the top-2 (other experts cancel exactly).
        const float r  = __expf(m2 - m1);  // <= 1
        const float w1 = 1.f / (1.f + r);
        const float w2 = 1.f - w1;

        const bool leader = ((lane & 7) == 0) && (lane < 16);  // lanes 0 and 8
        const int  tok    = t_base + (lane >> 3);
        if (leader) {
            out[tok * 2 + 0] = w1;
            out[tok * 2 + 1] = w2;
            out[2 * T_TOKENS + tok * 2 + 0] = (float)i1;  // indices as f32
            out[2 * T_TOKENS + tok * 2 + 1] = (float)i2;
            // Per-token expert counts into the block-level LDS histogram.
            atomicAdd(&hist[i1], 1);
            atomicAdd(&hist[i2], 1);
        }
    }
    __syncthreads();

    // Plain stores to this block's private slot. No global atomics, no fence.
    if (tid < NEXP) gpart[blockIdx.x * NEXP + tid] = hist[tid];
}

// Reduce the 512x8 partial-histogram table and compute the aux loss.
// Kernel boundary provides the global visibility ordering.
__global__ void router_aux(const int* __restrict__ gpart, float* __restrict__ out) {
    __shared__ int part[256];
    const int t = threadIdx.x;
    int s = 0;
#pragma unroll
    for (int i = 0; i < (NBLOCKS * NEXP) / 256; ++i)  // 16 iters, coalesced
        s += gpart[i * 256 + t];
    part[t] = s;  // thread t's sum is purely expert t&7 (256 % 8 == 0)
    __syncthreads();
    if (t < NEXP) {
        int c = 0;
#pragma unroll
        for (int i = 0; i < 256 / NEXP; ++i) c += part[t + i * NEXP];
        part[t] = c;  // per-expert total
    }
    __syncthreads();
    if (t == 0) {
        float m[NEXP];
        float ssum = 0.f;
#pragma unroll
        for (int e = 0; e < NEXP; ++e) {
            m[e] = (float)part[e] / (float)T_TOKENS;
            ssum += m[e];
        }
        const float mean = ssum / (float)NEXP;
        float var = 0.f;
#pragma unroll
        for (int e = 0; e < NEXP; ++e) {
            float d = m[e] - mean;
            var += d * d;
        }
        var /= (float)(NEXP - 1);            // unbiased (ddof=1), matches torch.var
        out[4 * T_TOKENS] = var * (float)NEXP;
    }
}

extern "C" void kernel_launch(void* const* d_in, const int* in_sizes, int n_in,
                              void* d_out, int out_size, void* d_ws, size_t ws_size,
                              hipStream_t stream) {
    const float* x  = (const float*)d_in[0];
    const float* gw = (const float*)d_in[1];
    float* out = (float*)d_out;
    int* gpart = (int*)d_ws;  // NBLOCKS*NEXP ints = 16 KB; every slot written,
                              // so no memset dispatch needed.

    router_fused<<<NBLOCKS, 512, 0, stream>>>(x, gw, out, gpart);
    router_aux<<<1, 256, 0, stream>>>(gpart, out);
}

// Round 14
// 192.969 us; speedup vs baseline: 1.3909x; 1.1883x over previous
//
#include <hip/hip_runtime.h>
#include <stdint.h>

// Problem constants (fixed by the reference)
#define T_TOKENS 16384   // B*S = 4*4096
#define HDIM     2048
#define NEXP     8
#define NCHUNK   (HDIM / 256)                    // 8 chunks of 256 floats
#define TPW      2                               // tokens per wave
#define WPB      8                               // waves per block (512 threads)
#define TOK_PER_BLOCK (WPB * TPW)                // 16
#define NBLOCKS  (T_TOKENS / TOK_PER_BLOCK)      // 1024

typedef const __attribute__((address_space(1))) uint32_t* gas_ptr;
typedef __attribute__((address_space(3))) uint32_t*       las_ptr;

__device__ __forceinline__ float dot4(float4 a, float4 b) {
    return a.x * b.x + a.y * b.y + a.z * b.z + a.w * b.w;
}

// Value-splitting butterfly stage: 2*D live accumulators -> D.
template <int D>
__device__ __forceinline__ void reduce_stage(float (&acc)[TPW * NEXP], int lane) {
    const bool upper = (lane & D) != 0;
#pragma unroll
    for (int i = 0; i < D; ++i) {
        float send = upper ? acc[i] : acc[i + D];
        float recv = __shfl_xor(send, D, 64);
        float keep = upper ? acc[i + D] : acc[i];
        acc[i] = keep + recv;
    }
}

// Rounds 12-13 post-mortem: the barrier-free NITER=2 schedule spilled at BOTH
// allocator tiers ((512,4): VGPR 64, 196 MB scratch; (512,2): VGPR 128, 68 MB
// scratch) because xv[2][8] stays live across the reduce/top-2/store tail.
// The allocator targets occupancy tiers (64/128 VGPR) and spills overflow.
// REVERT to the proven Round-6 one-shot body (VGPR 60, WRITE 568 KB = no
// spill, best measured bench 192.6 us), keeping ONE lesson: bounds (512,2)
// instead of (512,4). Occupancy is LDS-capped at 2 blocks/CU = 16 waves/CU
// either way (128 VGPR still supports 16 waves/CU), but the relaxed cap lets
// the allocator keep all 16 x-loads in flight instead of chunking them.
__global__ __launch_bounds__(512, 2) void router_fused(
    const float* __restrict__ x, const float* __restrict__ gate_w,
    float* __restrict__ out, int* __restrict__ gpart) {
    __shared__ float lds_gate[NEXP * HDIM];  // 65536 bytes
    __shared__ int   hist[NEXP];

    const int tid  = threadIdx.x;
    const int lane = tid & 63;
    const int wave = tid >> 6;
    if (tid < NEXP) hist[tid] = 0;

    // Stage gate_w (8x2048 f32 = 64 KB) via async global->LDS DMA: per wave,
    // 8 issues x 1 KB. Zero VGPR round-trip for gate data (round-5 verified).
    const float4* g4 = (const float4*)gate_w;
    float4* l4 = (float4*)lds_gate;
#pragma unroll
    for (int i = 0; i < (NEXP * HDIM / 4) / 512; ++i) {
        __builtin_amdgcn_global_load_lds(
            (gas_ptr)(g4 + i * 512 + wave * 64 + lane),
            (las_ptr)(l4 + i * 512 + wave * 64), 16, 0, 0);
    }

    const int t_base = (blockIdx.x * WPB + wave) * TPW;  // exact cover of T_TOKENS

    // Issue ALL x loads for this wave's 2 tokens up-front (16 dwordx4 in flight).
    const float4* x4 = (const float4*)x;
    const int row = HDIM / 4;  // 512 float4 per token
    float4 xv[TPW][NCHUNK];
#pragma unroll
    for (int t = 0; t < TPW; ++t)
#pragma unroll
        for (int c = 0; c < NCHUNK; ++c)
            xv[t][c] = x4[(size_t)(t_base + t) * row + c * 64 + lane];

    float acc[TPW * NEXP];
#pragma unroll
    for (int v = 0; v < TPW * NEXP; ++v) acc[v] = 0.f;

    __syncthreads();  // drains vmcnt(0): gate DMA + x loads complete; hist init

    // Pure LDS + FMA block; all indices compile-time (full unroll).
#pragma unroll
    for (int c = 0; c < NCHUNK; ++c) {
#pragma unroll
        for (int e = 0; e < NEXP; ++e) {
            float4 gv = l4[e * row + c * 64 + lane];
#pragma unroll
            for (int t = 0; t < TPW; ++t)
                acc[t * NEXP + e] += dot4(xv[t][c], gv);
        }
    }

    // Cross-lane reduce: 16 values over 64 lanes (bits 0-3), then fold 16/32.
    reduce_stage<8>(acc, lane);
    reduce_stage<4>(acc, lane);
    reduce_stage<2>(acc, lane);
    reduce_stage<1>(acc, lane);
    float v = acc[0];
    v += __shfl_xor(v, 16, 64);
    v += __shfl_xor(v, 32, 64);
    // Lane l holds the full logit for token t_base + ((l>>3)&1), expert l&7.
    const float logit = v;

    // Gather this token-group's 8 logits (source lane shares bit 3 = token bit).
    const int base = lane & 56;
    float lg[NEXP];
#pragma unroll
    for (int e = 0; e < NEXP; ++e) lg[e] = __shfl(logit, base + e, 64);

    // top-2, lowest index wins ties (matches jax.lax.top_k)
    int i1 = 0; float m1 = lg[0];
#pragma unroll
    for (int e = 1; e < NEXP; ++e) {
        if (lg[e] > m1) { m1 = lg[e]; i1 = e; }
    }
    int i2 = 1; float m2 = -3.4e38f;
#pragma unroll
    for (int e = 0; e < NEXP; ++e) {
        if (e != i1 && lg[e] > m2) { m2 = lg[e]; i2 = e; }
    }

    // Renormalized softmax over the top-2 (other experts cancel exactly).
    const float r  = __expf(m2 - m1);  // <= 1
    const float w1 = 1.f / (1.f + r);
    const float w2 = 1.f - w1;

    const bool leader = ((lane & 7) == 0) && (lane < 16);  // lanes 0 and 8
    const int  tok    = t_base + (lane >> 3);
    if (leader) {
        out[tok * 2 + 0] = w1;
        out[tok * 2 + 1] = w2;
        out[2 * T_TOKENS + tok * 2 + 0] = (float)i1;  // indices as f32 (flat f32 out)
        out[2 * T_TOKENS + tok * 2 + 1] = (float)i2;
        // Per-token expert counts into the block-level LDS histogram.
        atomicAdd(&hist[i1], 1);
        atomicAdd(&hist[i2], 1);
    }
    __syncthreads();

    // Plain stores to this block's private slot. No global atomics, no fence.
    if (tid < NEXP) gpart[blockIdx.x * NEXP + tid] = hist[tid];
}

// Reduce the 1024x8 partial-histogram table and compute the aux loss.
// Kernel boundary provides the global visibility ordering.
__global__ void router_aux(const int* __restrict__ gpart, float* __restrict__ out) {
    __shared__ int part[256];
    const int t = threadIdx.x;
    int s = 0;
#pragma unroll
    for (int i = 0; i < (NBLOCKS * NEXP) / 256; ++i)  // 32 iters, coalesced
        s += gpart[i * 256 + t];
    part[t] = s;  // thread t's sum is purely expert t&7 (256 % 8 == 0)
    __syncthreads();
    if (t < NEXP) {
        int c = 0;
#pragma unroll
        for (int i = 0; i < 256 / NEXP; ++i) c += part[t + i * NEXP];
        part[t] = c;  // per-expert total
    }
    __syncthreads();
    if (t == 0) {
        float m[NEXP];
        float ssum = 0.f;
#pragma unroll
        for (int e = 0; e < NEXP; ++e) {
            m[e] = (float)part[e] / (float)T_TOKENS;
            ssum += m[e];
        }
        const float mean = ssum / (float)NEXP;
        float var = 0.f;
#pragma unroll
        for (int e = 0; e < NEXP; ++e) {
            float d = m[e] - mean;
            var += d * d;
        }
        var /= (float)(NEXP - 1);            // unbiased (ddof=1), matches torch.var
        out[4 * T_TOKENS] = var * (float)NEXP;
    }
}

extern "C" void kernel_launch(void* const* d_in, const int* in_sizes, int n_in,
                              void* d_out, int out_size, void* d_ws, size_t ws_size,
                              hipStream_t stream) {
    const float* x  = (const float*)d_in[0];
    const float* gw = (const float*)d_in[1];
    float* out = (float*)d_out;
    int* gpart = (int*)d_ws;  // NBLOCKS*NEXP ints = 32 KB; every slot written,
                              // so no memset dispatch needed.

    router_fused<<<NBLOCKS, 512, 0, stream>>>(x, gw, out, gpart);
    router_aux<<<1, 256, 0, stream>>>(gpart, out);
}